// Round 2
// baseline (1919.896 us; speedup 1.0000x reference)
//
#include <hip/hip_runtime.h>

#define C 48
#define C4 192
#define HW 192
#define NPIX (HW * HW)          // 36864
#define BATCH 8
#define CNT (BATCH * NPIX)      // 294912 samples per channel for BN

// Workspace layout (float offsets). Total ~54.6 MiB.
#define APRE_OFF   0ull                          // [B][48][N]  (atten_pre -> mid in place)
#define G_OFF      14155776ull                   // [4][B][48][48] Gram matrices
#define STATS_OFF  14229504ull                   // 192 floats: bn1 sum, bn1 sq, bn2 sum, bn2 sq
#define M2_OFF     14229696ull                   // [B][4][48][48]  ([b][s][c][o])

// ---------------------------------------------------------------- k_gram
// G[s,b,c,d] = sum_n X0[b,c,n] * Xs[b,d,n]   (X0=input, X1..3 = fb,fc,fd)
__global__ __launch_bounds__(256) void k_gram(
    const float* __restrict__ x0, const float* __restrict__ x1,
    const float* __restrict__ x2, const float* __restrict__ x3,
    float* __restrict__ G)
{
    __shared__ float tile[C4 * 68];   // rows: 0..47=X0, 48..95=X1, 96..143=X2, 144..191=X3
    int b = blockIdx.y;
    int n0 = blockIdx.x * 512;
    int tid = threadIdx.x;
    int tc = tid & 15, td = tid >> 4;

    const float* xs[4] = { x0 + (size_t)b * C * NPIX, x1 + (size_t)b * C * NPIX,
                           x2 + (size_t)b * C * NPIX, x3 + (size_t)b * C * NPIX };

    float acc[4][3][3] = {};

    for (int st = 0; st < 8; ++st) {
        int nb = n0 + st * 64;
        __syncthreads();
#pragma unroll
        for (int k = 0; k < 12; ++k) {
            int idx = tid + k * 256;
            int ch = idx >> 4, nq = (idx & 15) * 4;
            int s = ch / C, c = ch % C;
            *(float4*)&tile[ch * 68 + nq] =
                *(const float4*)(xs[s] + (size_t)c * NPIX + nb + nq);
        }
        __syncthreads();
#pragma unroll
        for (int n4 = 0; n4 < 16; ++n4) {
            float4 qv[3];
#pragma unroll
            for (int ci = 0; ci < 3; ++ci)
                qv[ci] = *(const float4*)&tile[(tc + 16 * ci) * 68 + n4 * 4];
#pragma unroll
            for (int s = 0; s < 4; ++s)
#pragma unroll
                for (int di = 0; di < 3; ++di) {
                    float4 kv = *(const float4*)&tile[(s * C + td + 16 * di) * 68 + n4 * 4];
#pragma unroll
                    for (int ci = 0; ci < 3; ++ci)
                        acc[s][ci][di] += qv[ci].x * kv.x + qv[ci].y * kv.y
                                        + qv[ci].z * kv.z + qv[ci].w * kv.w;
                }
        }
    }
#pragma unroll
    for (int s = 0; s < 4; ++s)
#pragma unroll
        for (int ci = 0; ci < 3; ++ci)
#pragma unroll
            for (int di = 0; di < 3; ++di) {
                int c = tc + 16 * ci, d = td + 16 * di;
                atomicAdd(&G[(((size_t)s * BATCH + b) * C + c) * C + d],
                          acc[s][ci][di]);
            }
}

// ---------------------------------------------------------------- k_small
// Per (s,b): E = Wa * (G_s * Ws^T); att = reversed softmax rows of E;
// M[d][o] = sum_c fuse_w[o, s*48+c] * att[c,d];
// M2[c][o] = sum_d Ws[d,c] * M[d][o]  -> global [b][s][c][o]
__global__ __launch_bounds__(256) void k_small(
    const float* __restrict__ G,
    const float* __restrict__ Wa, const float* __restrict__ Wb,
    const float* __restrict__ Wc, const float* __restrict__ Wd,
    const float* __restrict__ fuse_w, float* __restrict__ M2g)
{
    int s = blockIdx.x, b = blockIdx.y;
    const float* Ws = (s == 0) ? Wa : (s == 1) ? Wb : (s == 2) ? Wc : Wd;

    __shared__ float g[C * C], wsm[C * C], wam[C * C], fw[C * C];
    __shared__ float t[C * C], e[C * C], m[C * C];
    int tid = threadIdx.x;

    const float* Gb = G + ((size_t)s * BATCH + b) * C * C;
    for (int k = tid; k < C * C; k += 256) {
        g[k] = Gb[k];
        wsm[k] = Ws[k];
        wam[k] = Wa[k];
        int o = k / C, c = k % C;
        fw[k] = fuse_w[(size_t)o * C4 + s * C + c];   // [o][c]
    }
    __syncthreads();

    // T[c,d] = sum_e G[c,e] * Ws[d,e]
    for (int k = tid; k < C * C; k += 256) {
        int c = k / C, d = k % C;
        float a = 0.f;
        for (int q = 0; q < C; ++q) a += g[c * C + q] * wsm[d * C + q];
        t[k] = a;
    }
    __syncthreads();
    // E[c,d] = sum_e Wa[c,e] * T[e,d]
    for (int k = tid; k < C * C; k += 256) {
        int c = k / C, d = k % C;
        float a = 0.f;
        for (int q = 0; q < C; ++q) a += wam[c * C + q] * t[q * C + d];
        e[k] = a;
    }
    __syncthreads();
    // reversed softmax per row c: att[c,d] = exp(min_d - e) / sum
    if (tid < C) {
        int c = tid;
        float mn = e[c * C];
        for (int d = 1; d < C; ++d) mn = fminf(mn, e[c * C + d]);
        float sum = 0.f;
        for (int d = 0; d < C; ++d) {
            float v = __expf(mn - e[c * C + d]);
            e[c * C + d] = v;
            sum += v;
        }
        float inv = 1.0f / sum;
        for (int d = 0; d < C; ++d) e[c * C + d] *= inv;
    }
    __syncthreads();
    // M[d][o] = sum_c fw[o][c] * att[c,d]
    for (int k = tid; k < C * C; k += 256) {
        int d = k / C, o = k % C;
        float a = 0.f;
        for (int q = 0; q < C; ++q) a += fw[o * C + q] * e[q * C + d];
        m[k] = a;
    }
    __syncthreads();
    // M2[c][o] = sum_d Ws[d,c] * M[d][o]
    float* out = M2g + ((size_t)b * 4 + s) * C * C;
    for (int k = tid; k < C * C; k += 256) {
        int c = k / C, o = k % C;
        float a = 0.f;
        for (int q = 0; q < C; ++q) a += wsm[q * C + c] * m[q * C + o];
        out[k] = a;
    }
}

// ---------------------------------------------------------------- k_apply
// apre[b,o,n] = sum_s sum_c M2[b][s][c][o] * Xs[b,c,n] + fuse_b[o]; + BN1 stats
__global__ __launch_bounds__(256) void k_apply(
    const float* __restrict__ x0, const float* __restrict__ x1,
    const float* __restrict__ x2, const float* __restrict__ x3,
    const float* __restrict__ M2g, const float* __restrict__ fuse_b,
    float* __restrict__ apre, float* __restrict__ stats)
{
    int b = blockIdx.y;
    __shared__ float ml[4 * C * C];    // [s][c][o]
    int tid = threadIdx.x;
    const float* Mb = M2g + (size_t)b * 4 * C * C;
    for (int k = tid; k < 4 * C * C; k += 256) ml[k] = Mb[k];
    __syncthreads();

    int nt = tid & 63, og = tid >> 6, o0 = og * 12;
    int n = blockIdx.x * 256 + nt * 4;
    const float* xs[4] = { x0 + (size_t)b * C * NPIX + n, x1 + (size_t)b * C * NPIX + n,
                           x2 + (size_t)b * C * NPIX + n, x3 + (size_t)b * C * NPIX + n };

    float4 acc[12];
#pragma unroll
    for (int j = 0; j < 12; ++j) acc[j] = make_float4(0.f, 0.f, 0.f, 0.f);

#pragma unroll
    for (int s = 0; s < 4; ++s) {
        const float* xb = xs[s];
        const float* mls = ml + s * C * C + o0;
        for (int c = 0; c < C; ++c) {
            float4 xv = *(const float4*)(xb + (size_t)c * NPIX);
#pragma unroll
            for (int jj = 0; jj < 12; ++jj) {
                float wv = mls[c * C + jj];   // wave-uniform -> broadcast
                acc[jj].x += wv * xv.x; acc[jj].y += wv * xv.y;
                acc[jj].z += wv * xv.z; acc[jj].w += wv * xv.w;
            }
        }
    }

    float* ab = apre + ((size_t)b * C + o0) * NPIX + n;
#pragma unroll
    for (int jj = 0; jj < 12; ++jj) {
        float fb = fuse_b[o0 + jj];
        acc[jj].x += fb; acc[jj].y += fb; acc[jj].z += fb; acc[jj].w += fb;
        *(float4*)(ab + (size_t)jj * NPIX) = acc[jj];
    }
#pragma unroll
    for (int jj = 0; jj < 12; ++jj) {
        float4 v = acc[jj];
        float s1 = v.x + v.y + v.z + v.w;
        float s2 = v.x * v.x + v.y * v.y + v.z * v.z + v.w * v.w;
        for (int off = 32; off; off >>= 1) {
            s1 += __shfl_down(s1, off, 64);
            s2 += __shfl_down(s2, off, 64);
        }
        if (nt == 0) {
            atomicAdd(&stats[o0 + jj], s1);
            atomicAdd(&stats[C + o0 + jj], s2);
        }
    }
}

// ---------------------------------------------------------------- k_bn1
// mid = gamma_cam * relu(BN(atten_pre)) + input   (in place on apre)
__global__ __launch_bounds__(256) void k_bn1(
    float* __restrict__ apre, const float* __restrict__ inp,
    const float* __restrict__ stats, const float* __restrict__ gamma,
    const float* __restrict__ beta, const float* __restrict__ gcam)
{
    size_t i = ((size_t)blockIdx.x * 256 + threadIdx.x) * 4;
    int c = (int)((i / NPIX) % C);
    const float invc = 1.0f / (float)CNT;
    float mu = stats[c] * invc;
    float var = stats[C + c] * invc - mu * mu;
    float sc = gamma[c] * rsqrtf(var + 1e-5f);
    float be = beta[c] - mu * sc;
    float g = gcam[0];

    float4 v = *(float4*)(apre + i);
    float4 x = *(const float4*)(inp + i);
    v.x = fmaxf(v.x * sc + be, 0.f) * g + x.x;
    v.y = fmaxf(v.y * sc + be, 0.f) * g + x.y;
    v.z = fmaxf(v.z * sc + be, 0.f) * g + x.z;
    v.w = fmaxf(v.w * sc + be, 0.f) * g + x.w;
    *(float4*)(apre + i) = v;
}

// ---------------------------------------------------------------- k_conv
// 3x3 conv, pad 1. 32x32 pixel tile per block, 12 outputs per block (z), BN2 stats.
__global__ __launch_bounds__(256) void k_conv(
    const float* __restrict__ mid, const float* __restrict__ wgt,
    const float* __restrict__ bias, float* __restrict__ out,
    float* __restrict__ stats)
{
    int b = blockIdx.y, og = blockIdx.z, o0 = og * 12;
    int tx = blockIdx.x % 6, ty = blockIdx.x / 6;
    int h0 = ty * 32, w0 = tx * 32;
    __shared__ float xl[34 * 36];
    int tid = threadIdx.x;
    int r = tid >> 3, c4 = (tid & 7) * 4;

    float acc[12][4] = {};

    for (int i = 0; i < C; ++i) {
        __syncthreads();
        const float* mb = mid + ((size_t)b * C + i) * NPIX;
        for (int e2 = tid; e2 < 34 * 34; e2 += 256) {
            int rr = e2 / 34, cc = e2 % 34;
            int h = h0 - 1 + rr, w = w0 - 1 + cc;
            float v = 0.f;
            if (h >= 0 && h < HW && w >= 0 && w < HW) v = mb[h * HW + w];
            xl[rr * 36 + cc] = v;
        }
        __syncthreads();
        const float* wi = wgt + (size_t)(o0 * C + i) * 9;
#pragma unroll
        for (int kh = 0; kh < 3; ++kh) {
            float xr[6];
#pragma unroll
            for (int tt = 0; tt < 6; ++tt) xr[tt] = xl[(r + kh) * 36 + c4 + tt];
#pragma unroll
            for (int kw = 0; kw < 3; ++kw) {
#pragma unroll
                for (int j = 0; j < 12; ++j) {
                    float wv = wi[(size_t)j * C * 9 + kh * 3 + kw];  // uniform -> s_load
                    acc[j][0] += wv * xr[kw];
                    acc[j][1] += wv * xr[kw + 1];
                    acc[j][2] += wv * xr[kw + 2];
                    acc[j][3] += wv * xr[kw + 3];
                }
            }
        }
    }

    int h = h0 + r, w = w0 + c4;
#pragma unroll
    for (int j = 0; j < 12; ++j) {
        float bb = bias[o0 + j];
        float4 v = make_float4(acc[j][0] + bb, acc[j][1] + bb,
                               acc[j][2] + bb, acc[j][3] + bb);
        *(float4*)(out + ((size_t)b * C + o0 + j) * NPIX + h * HW + w) = v;
        float s1 = v.x + v.y + v.z + v.w;
        float s2 = v.x * v.x + v.y * v.y + v.z * v.z + v.w * v.w;
        for (int off = 32; off; off >>= 1) {
            s1 += __shfl_down(s1, off, 64);
            s2 += __shfl_down(s2, off, 64);
        }
        if ((tid & 63) == 0) {
            atomicAdd(&stats[2 * C + o0 + j], s1);
            atomicAdd(&stats[3 * C + o0 + j], s2);
        }
    }
}

// ---------------------------------------------------------------- k_bn2
__global__ __launch_bounds__(256) void k_bn2(
    float* __restrict__ out, const float* __restrict__ stats,
    const float* __restrict__ gamma, const float* __restrict__ beta)
{
    size_t i = ((size_t)blockIdx.x * 256 + threadIdx.x) * 4;
    int c = (int)((i / NPIX) % C);
    const float invc = 1.0f / (float)CNT;
    float mu = stats[2 * C + c] * invc;
    float var = stats[3 * C + c] * invc - mu * mu;
    float sc = gamma[c] * rsqrtf(var + 1e-5f);
    float be = beta[c] - mu * sc;

    float4 v = *(float4*)(out + i);
    v.x = fmaxf(v.x * sc + be, 0.f);
    v.y = fmaxf(v.y * sc + be, 0.f);
    v.z = fmaxf(v.z * sc + be, 0.f);
    v.w = fmaxf(v.w * sc + be, 0.f);
    *(float4*)(out + i) = v;
}

// ---------------------------------------------------------------- launch
extern "C" void kernel_launch(void* const* d_in, const int* in_sizes, int n_in,
                              void* d_out, int out_size, void* d_ws, size_t ws_size,
                              hipStream_t stream)
{
    const float* inp   = (const float*)d_in[0];
    const float* fb    = (const float*)d_in[1];
    const float* fc    = (const float*)d_in[2];
    const float* fd    = (const float*)d_in[3];
    const float* Wa    = (const float*)d_in[4];
    const float* Wb    = (const float*)d_in[5];
    const float* Wc    = (const float*)d_in[6];
    const float* Wd    = (const float*)d_in[7];
    const float* fusew = (const float*)d_in[8];
    const float* fuseb = (const float*)d_in[9];
    const float* fgam  = (const float*)d_in[10];
    const float* fbet  = (const float*)d_in[11];
    const float* gcam  = (const float*)d_in[12];
    const float* outw  = (const float*)d_in[13];
    const float* outb  = (const float*)d_in[14];
    const float* ogam  = (const float*)d_in[15];
    const float* obet  = (const float*)d_in[16];

    float* ws    = (float*)d_ws;
    float* apre  = ws + APRE_OFF;
    float* G     = ws + G_OFF;
    float* stats = ws + STATS_OFF;
    float* M2g   = ws + M2_OFF;
    float* out   = (float*)d_out;

    // zero G + stats (contiguous)
    hipMemsetAsync(G, 0, (73728ull + 192ull) * sizeof(float), stream);

    k_gram<<<dim3(72, BATCH), 256, 0, stream>>>(inp, fb, fc, fd, G);
    k_small<<<dim3(4, BATCH), 256, 0, stream>>>(G, Wa, Wb, Wc, Wd, fusew, M2g);
    k_apply<<<dim3(144, BATCH), 256, 0, stream>>>(inp, fb, fc, fd, M2g, fuseb, apre, stats);
    k_bn1<<<13824, 256, 0, stream>>>(apre, inp, stats, fgam, fbet, gcam);
    k_conv<<<dim3(36, BATCH, 4), 256, 0, stream>>>(apre, outw, outb, out, stats);
    k_bn2<<<13824, 256, 0, stream>>>(out, stats, ogam, obet);
}

// Round 3
// 1364.417 us; speedup vs baseline: 1.4071x; 1.4071x over previous
//
#include <hip/hip_runtime.h>

#define C 48
#define C4 192
#define HW 192
#define NPIX (HW * HW)          // 36864
#define BATCH 8
#define CNT (BATCH * NPIX)      // 294912 samples per channel for BN

// Workspace layout. Total ~85.6 MB.
//   floats: apre [B][48][N] @0 ; G [4][B][48][48] ; stats[192] ; M2 [B][4][48][48]
//   shorts (bf16): mid_t [B][N][48] ; Wb [9][48][64]
#define APRE_OFF   0ull
#define G_OFF      14155776ull
#define STATS_OFF  14229504ull
#define M2_OFF     14229696ull
#define MIDT_BYTE  57213696ull                   // 4 * 14303424
#define WB_BYTE    85525248ull                   // MIDT + 28311552

typedef __attribute__((ext_vector_type(8))) short short8;
typedef __attribute__((ext_vector_type(4))) float f32x4;

static __device__ __forceinline__ short f2bf(float f) {
    unsigned u = __float_as_uint(f);
    unsigned r = (u + 0x7fffu + ((u >> 16) & 1u)) >> 16;
    return (short)r;
}

// ---------------------------------------------------------------- k_gram
// G[s,b,c,d] = sum_n X0[b,c,n] * Xs[b,d,n]
__global__ __launch_bounds__(256) void k_gram(
    const float* __restrict__ x0, const float* __restrict__ x1,
    const float* __restrict__ x2, const float* __restrict__ x3,
    float* __restrict__ G)
{
    __shared__ float tile[C4 * 68];
    int b = blockIdx.y;
    int n0 = blockIdx.x * 512;
    int tid = threadIdx.x;
    int tc = tid & 15, td = tid >> 4;

    const float* xs[4] = { x0 + (size_t)b * C * NPIX, x1 + (size_t)b * C * NPIX,
                           x2 + (size_t)b * C * NPIX, x3 + (size_t)b * C * NPIX };

    float acc[4][3][3] = {};

    for (int st = 0; st < 8; ++st) {
        int nb = n0 + st * 64;
        __syncthreads();
#pragma unroll
        for (int k = 0; k < 12; ++k) {
            int idx = tid + k * 256;
            int ch = idx >> 4, nq = (idx & 15) * 4;
            int s = ch / C, c = ch % C;
            *(float4*)&tile[ch * 68 + nq] =
                *(const float4*)(xs[s] + (size_t)c * NPIX + nb + nq);
        }
        __syncthreads();
#pragma unroll
        for (int n4 = 0; n4 < 16; ++n4) {
            float4 qv[3];
#pragma unroll
            for (int ci = 0; ci < 3; ++ci)
                qv[ci] = *(const float4*)&tile[(tc + 16 * ci) * 68 + n4 * 4];
#pragma unroll
            for (int s = 0; s < 4; ++s)
#pragma unroll
                for (int di = 0; di < 3; ++di) {
                    float4 kv = *(const float4*)&tile[(s * C + td + 16 * di) * 68 + n4 * 4];
#pragma unroll
                    for (int ci = 0; ci < 3; ++ci)
                        acc[s][ci][di] += qv[ci].x * kv.x + qv[ci].y * kv.y
                                        + qv[ci].z * kv.z + qv[ci].w * kv.w;
                }
        }
    }
#pragma unroll
    for (int s = 0; s < 4; ++s)
#pragma unroll
        for (int ci = 0; ci < 3; ++ci)
#pragma unroll
            for (int di = 0; di < 3; ++di) {
                int c = tc + 16 * ci, d = td + 16 * di;
                atomicAdd(&G[(((size_t)s * BATCH + b) * C + c) * C + d],
                          acc[s][ci][di]);
            }
}

// ---------------------------------------------------------------- k_small
__global__ __launch_bounds__(256) void k_small(
    const float* __restrict__ G,
    const float* __restrict__ Wa, const float* __restrict__ Wb,
    const float* __restrict__ Wc, const float* __restrict__ Wd,
    const float* __restrict__ fuse_w, float* __restrict__ M2g)
{
    int s = blockIdx.x, b = blockIdx.y;
    const float* Ws = (s == 0) ? Wa : (s == 1) ? Wb : (s == 2) ? Wc : Wd;

    __shared__ float g[C * C], wsm[C * C], wam[C * C], fw[C * C];
    __shared__ float t[C * C], e[C * C], m[C * C];
    int tid = threadIdx.x;

    const float* Gb = G + ((size_t)s * BATCH + b) * C * C;
    for (int k = tid; k < C * C; k += 256) {
        g[k] = Gb[k];
        wsm[k] = Ws[k];
        wam[k] = Wa[k];
        int o = k / C, c = k % C;
        fw[k] = fuse_w[(size_t)o * C4 + s * C + c];
    }
    __syncthreads();

    for (int k = tid; k < C * C; k += 256) {
        int c = k / C, d = k % C;
        float a = 0.f;
        for (int q = 0; q < C; ++q) a += g[c * C + q] * wsm[d * C + q];
        t[k] = a;
    }
    __syncthreads();
    for (int k = tid; k < C * C; k += 256) {
        int c = k / C, d = k % C;
        float a = 0.f;
        for (int q = 0; q < C; ++q) a += wam[c * C + q] * t[q * C + d];
        e[k] = a;
    }
    __syncthreads();
    if (tid < C) {
        int c = tid;
        float mn = e[c * C];
        for (int d = 1; d < C; ++d) mn = fminf(mn, e[c * C + d]);
        float sum = 0.f;
        for (int d = 0; d < C; ++d) {
            float v = __expf(mn - e[c * C + d]);
            e[c * C + d] = v;
            sum += v;
        }
        float inv = 1.0f / sum;
        for (int d = 0; d < C; ++d) e[c * C + d] *= inv;
    }
    __syncthreads();
    for (int k = tid; k < C * C; k += 256) {
        int d = k / C, o = k % C;
        float a = 0.f;
        for (int q = 0; q < C; ++q) a += fw[o * C + q] * e[q * C + d];
        m[k] = a;
    }
    __syncthreads();
    float* out = M2g + ((size_t)b * 4 + s) * C * C;
    for (int k = tid; k < C * C; k += 256) {
        int c = k / C, o = k % C;
        float a = 0.f;
        for (int q = 0; q < C; ++q) a += wsm[q * C + c] * m[q * C + o];
        out[k] = a;
    }
}

// ---------------------------------------------------------------- k_apply
__global__ __launch_bounds__(256) void k_apply(
    const float* __restrict__ x0, const float* __restrict__ x1,
    const float* __restrict__ x2, const float* __restrict__ x3,
    const float* __restrict__ M2g, const float* __restrict__ fuse_b,
    float* __restrict__ apre, float* __restrict__ stats)
{
    int b = blockIdx.y;
    __shared__ float ml[4 * C * C];
    int tid = threadIdx.x;
    const float* Mb = M2g + (size_t)b * 4 * C * C;
    for (int k = tid; k < 4 * C * C; k += 256) ml[k] = Mb[k];
    __syncthreads();

    int nt = tid & 63, og = tid >> 6, o0 = og * 12;
    int n = blockIdx.x * 256 + nt * 4;
    const float* xs[4] = { x0 + (size_t)b * C * NPIX + n, x1 + (size_t)b * C * NPIX + n,
                           x2 + (size_t)b * C * NPIX + n, x3 + (size_t)b * C * NPIX + n };

    float4 acc[12];
#pragma unroll
    for (int j = 0; j < 12; ++j) acc[j] = make_float4(0.f, 0.f, 0.f, 0.f);

#pragma unroll
    for (int s = 0; s < 4; ++s) {
        const float* xb = xs[s];
        const float* mls = ml + s * C * C + o0;
        for (int c = 0; c < C; ++c) {
            float4 xv = *(const float4*)(xb + (size_t)c * NPIX);
#pragma unroll
            for (int jj = 0; jj < 12; ++jj) {
                float wv = mls[c * C + jj];
                acc[jj].x += wv * xv.x; acc[jj].y += wv * xv.y;
                acc[jj].z += wv * xv.z; acc[jj].w += wv * xv.w;
            }
        }
    }

    float* ab = apre + ((size_t)b * C + o0) * NPIX + n;
#pragma unroll
    for (int jj = 0; jj < 12; ++jj) {
        float fb = fuse_b[o0 + jj];
        acc[jj].x += fb; acc[jj].y += fb; acc[jj].z += fb; acc[jj].w += fb;
        *(float4*)(ab + (size_t)jj * NPIX) = acc[jj];
    }
#pragma unroll
    for (int jj = 0; jj < 12; ++jj) {
        float4 v = acc[jj];
        float s1 = v.x + v.y + v.z + v.w;
        float s2 = v.x * v.x + v.y * v.y + v.z * v.z + v.w * v.w;
        for (int off = 32; off; off >>= 1) {
            s1 += __shfl_down(s1, off, 64);
            s2 += __shfl_down(s2, off, 64);
        }
        if (nt == 0) {
            atomicAdd(&stats[o0 + jj], s1);
            atomicAdd(&stats[C + o0 + jj], s2);
        }
    }
}

// ---------------------------------------------------------------- k_bn1t
// mid_t[b,px,c] = bf16( gamma_cam * relu(BN(apre)) + input )  (transposed!)
__global__ __launch_bounds__(256) void k_bn1t(
    const float* __restrict__ apre, const float* __restrict__ inp,
    const float* __restrict__ stats, const float* __restrict__ gamma,
    const float* __restrict__ beta, const float* __restrict__ gcam,
    short* __restrict__ mid_t)
{
    int c = blockIdx.y, b = blockIdx.z;
    int px = blockIdx.x * 1024 + threadIdx.x * 4;
    const float invc = 1.0f / (float)CNT;
    float mu = stats[c] * invc;
    float var = stats[C + c] * invc - mu * mu;
    float sc = gamma[c] * rsqrtf(var + 1e-5f);
    float be = beta[c] - mu * sc;
    float g = gcam[0];

    size_t base = ((size_t)b * C + c) * NPIX + px;
    float4 v = *(const float4*)(apre + base);
    float4 x = *(const float4*)(inp + base);
    v.x = fmaxf(v.x * sc + be, 0.f) * g + x.x;
    v.y = fmaxf(v.y * sc + be, 0.f) * g + x.y;
    v.z = fmaxf(v.z * sc + be, 0.f) * g + x.z;
    v.w = fmaxf(v.w * sc + be, 0.f) * g + x.w;

    short* mb = mid_t + ((size_t)b * NPIX + px) * C + c;
    mb[0 * C] = f2bf(v.x);
    mb[1 * C] = f2bf(v.y);
    mb[2 * C] = f2bf(v.z);
    mb[3 * C] = f2bf(v.w);
}

// ---------------------------------------------------------------- k_prep
// Wb[tap][o][i(64)] bf16 from out_w [o][i][kh][kw] fp32 (i>=48 -> 0)
__global__ __launch_bounds__(256) void k_prep(
    const float* __restrict__ outw, short* __restrict__ Wb)
{
    int idx = blockIdx.x * 256 + threadIdx.x;
    if (idx >= 9 * 48 * 64) return;
    int i = idx & 63;
    int o = (idx >> 6) % 48;
    int tap = idx / (64 * 48);
    float v = (i < C) ? outw[((size_t)o * C + i) * 9 + tap] : 0.f;
    Wb[idx] = f2bf(v);
}

// ---------------------------------------------------------------- k_conv_mfma
// 3x3 conv via 9-tap implicit GEMM, bf16 MFMA 16x16x32.
// Block: 16x16 out pixels, all 48 o. LDS: halo 18x18 px x 64ch (stride 72).
__global__ __launch_bounds__(256) void k_conv_mfma(
    const short* __restrict__ mid_t, const short* __restrict__ Wb,
    const float* __restrict__ bias, float* __restrict__ out,
    float* __restrict__ stats)
{
    __shared__ short xl[324 * 72];
    __shared__ float sst[96];
    int b = blockIdx.y;
    int ty = blockIdx.x / 12, tx = blockIdx.x % 12;
    int h0 = ty * 16, w0 = tx * 16;
    int tid = threadIdx.x;

    if (tid < 96) sst[tid] = 0.f;

    // stage halo tile: 324 px x (48 data + 16 zero pad) ch, 16B chunks
    for (int ch = tid; ch < 2916; ch += 256) {
        int lpx = ch / 9, part = ch % 9;
        int hh = h0 - 1 + lpx / 18, ww = w0 - 1 + lpx % 18;
        short8 v = {0, 0, 0, 0, 0, 0, 0, 0};
        if (part < 6 && hh >= 0 && hh < HW && ww >= 0 && ww < HW)
            v = *(const short8*)(mid_t + ((size_t)b * NPIX + hh * HW + ww) * C + part * 8);
        *(short8*)(xl + lpx * 72 + part * 8) = v;
    }
    __syncthreads();

    int wid = tid >> 6, lane = tid & 63;
    int col = lane & 15, quad = lane >> 4;

    f32x4 acc[3][4];
#pragma unroll
    for (int mt = 0; mt < 3; ++mt)
#pragma unroll
        for (int rr = 0; rr < 4; ++rr)
            acc[mt][rr] = (f32x4){0.f, 0.f, 0.f, 0.f};

#pragma unroll
    for (int tap = 0; tap < 9; ++tap) {
        int dh = tap / 3, dw = tap % 3;
#pragma unroll
        for (int kb = 0; kb < 2; ++kb) {
            short8 afr[3];
#pragma unroll
            for (int mt = 0; mt < 3; ++mt)
                afr[mt] = *(const short8*)(Wb + ((size_t)(tap * 48 + mt * 16 + col)) * 64
                                               + kb * 32 + quad * 8);
#pragma unroll
            for (int rr = 0; rr < 4; ++rr) {
                int r = wid * 4 + rr;
                int lpx = (r + dh) * 18 + col + dw;
                short8 bfr = *(const short8*)(xl + lpx * 72 + kb * 32 + quad * 8);
#pragma unroll
                for (int mt = 0; mt < 3; ++mt)
                    acc[mt][rr] = __builtin_amdgcn_mfma_f32_16x16x32_bf16(
                        afr[mt], bfr, acc[mt][rr], 0, 0, 0);
            }
        }
    }

    // epilogue: bias, store, BN2 stats
    float s1[3][4] = {}, s2[3][4] = {};
#pragma unroll
    for (int mt = 0; mt < 3; ++mt)
#pragma unroll
        for (int rr = 0; rr < 4; ++rr) {
            int r = wid * 4 + rr;
            f32x4 v = acc[mt][rr];
#pragma unroll
            for (int j = 0; j < 4; ++j) {
                int o = mt * 16 + quad * 4 + j;
                float val = v[j] + bias[o];
                out[((size_t)b * C + o) * NPIX + (h0 + r) * HW + w0 + col] = val;
                s1[mt][j] += val;
                s2[mt][j] += val * val;
            }
        }
#pragma unroll
    for (int mt = 0; mt < 3; ++mt)
#pragma unroll
        for (int j = 0; j < 4; ++j) {
            float a = s1[mt][j], q = s2[mt][j];
#pragma unroll
            for (int off = 8; off; off >>= 1) {
                a += __shfl_down(a, off, 16);
                q += __shfl_down(q, off, 16);
            }
            if (col == 0) {
                int o = mt * 16 + quad * 4 + j;
                atomicAdd(&sst[o], a);
                atomicAdd(&sst[48 + o], q);
            }
        }
    __syncthreads();
    if (tid < 48)       atomicAdd(&stats[2 * C + tid], sst[tid]);
    else if (tid < 96)  atomicAdd(&stats[3 * C + tid - 48], sst[tid]);
}

// ---------------------------------------------------------------- k_bn2
__global__ __launch_bounds__(256) void k_bn2(
    float* __restrict__ out, const float* __restrict__ stats,
    const float* __restrict__ gamma, const float* __restrict__ beta)
{
    size_t i = ((size_t)blockIdx.x * 256 + threadIdx.x) * 4;
    int c = (int)((i / NPIX) % C);
    const float invc = 1.0f / (float)CNT;
    float mu = stats[2 * C + c] * invc;
    float var = stats[3 * C + c] * invc - mu * mu;
    float sc = gamma[c] * rsqrtf(var + 1e-5f);
    float be = beta[c] - mu * sc;

    float4 v = *(float4*)(out + i);
    v.x = fmaxf(v.x * sc + be, 0.f);
    v.y = fmaxf(v.y * sc + be, 0.f);
    v.z = fmaxf(v.z * sc + be, 0.f);
    v.w = fmaxf(v.w * sc + be, 0.f);
    *(float4*)(out + i) = v;
}

// ---------------------------------------------------------------- launch
extern "C" void kernel_launch(void* const* d_in, const int* in_sizes, int n_in,
                              void* d_out, int out_size, void* d_ws, size_t ws_size,
                              hipStream_t stream)
{
    const float* inp   = (const float*)d_in[0];
    const float* fb    = (const float*)d_in[1];
    const float* fc    = (const float*)d_in[2];
    const float* fd    = (const float*)d_in[3];
    const float* Wa    = (const float*)d_in[4];
    const float* Wbm   = (const float*)d_in[5];
    const float* Wcm   = (const float*)d_in[6];
    const float* Wdm   = (const float*)d_in[7];
    const float* fusew = (const float*)d_in[8];
    const float* fuseb = (const float*)d_in[9];
    const float* fgam  = (const float*)d_in[10];
    const float* fbet  = (const float*)d_in[11];
    const float* gcam  = (const float*)d_in[12];
    const float* outw  = (const float*)d_in[13];
    const float* outb  = (const float*)d_in[14];
    const float* ogam  = (const float*)d_in[15];
    const float* obet  = (const float*)d_in[16];

    float* ws    = (float*)d_ws;
    float* apre  = ws + APRE_OFF;
    float* G     = ws + G_OFF;
    float* stats = ws + STATS_OFF;
    float* M2g   = ws + M2_OFF;
    short* mid_t = (short*)((char*)d_ws + MIDT_BYTE);
    short* Wb    = (short*)((char*)d_ws + WB_BYTE);
    float* out   = (float*)d_out;

    hipMemsetAsync(G, 0, (73728ull + 192ull) * sizeof(float), stream);

    k_prep<<<108, 256, 0, stream>>>(outw, Wb);
    k_gram<<<dim3(72, BATCH), 256, 0, stream>>>(inp, fb, fc, fd, G);
    k_small<<<dim3(4, BATCH), 256, 0, stream>>>(G, Wa, Wbm, Wcm, Wdm, fusew, M2g);
    k_apply<<<dim3(144, BATCH), 256, 0, stream>>>(inp, fb, fc, fd, M2g, fuseb, apre, stats);
    k_bn1t<<<dim3(36, 48, BATCH), 256, 0, stream>>>(apre, inp, stats, fgam, fbet, gcam, mid_t);
    k_conv_mfma<<<dim3(144, BATCH), 256, 0, stream>>>(mid_t, Wb, outb, out, stats);
    k_bn2<<<13824, 256, 0, stream>>>(out, stats, ogam, obet);
}

// Round 4
// 742.205 us; speedup vs baseline: 2.5867x; 1.8383x over previous
//
#include <hip/hip_runtime.h>
#include <hip/hip_bf16.h>

#define C 48
#define C4 192
#define HW 192
#define NPIX (HW * HW)          // 36864
#define BATCH 8
#define CNT (BATCH * NPIX)      // 294912 samples per channel for BN

// Workspace layout. Total ~85.6 MB.
#define APRE_OFF   0ull
#define G_OFF      14155776ull
#define STATS_OFF  14229504ull
#define M2_OFF     14229696ull
#define MIDT_BYTE  57213696ull
#define WB_BYTE    85525248ull

typedef __attribute__((ext_vector_type(8))) short short8;
typedef __attribute__((ext_vector_type(4))) float f32x4;

static __device__ __forceinline__ unsigned pkbf(float a, float b) {
    union { __hip_bfloat162 h; unsigned u; } t;
    t.h = __float22bfloat162_rn(make_float2(a, b));
    return t.u;                                   // low16 = bf16(a), high16 = bf16(b)
}
static __device__ __forceinline__ float lo2f(unsigned p) { return __uint_as_float(p << 16); }
static __device__ __forceinline__ float hi2f(unsigned p) { return __uint_as_float(p & 0xffff0000u); }
static __device__ __forceinline__ short f2bfs(float f) { return (short)(pkbf(f, f) & 0xffffu); }

// ---------------------------------------------------------------- k_gram_mfma
// G[s,b,c,d] = sum_n X0[b,c,n] * Xs[b,d,n] via bf16 hi/lo split MFMA (3 products).
// Block: 512-n chunk, all 48x192 outputs. LDS: [192 ch][64 n] hi+lo, stride 72.
__global__ __launch_bounds__(256) void k_gram_mfma(
    const float* __restrict__ x0, const float* __restrict__ x1,
    const float* __restrict__ x2, const float* __restrict__ x3,
    float* __restrict__ G)
{
    __shared__ short hibuf[C4 * 72];
    __shared__ short lobuf[C4 * 72];
    int b = blockIdx.y;
    int n0 = blockIdx.x * 512;
    int tid = threadIdx.x;
    int wid = tid >> 6, lane = tid & 63, col = lane & 15, quad = lane >> 4;

    const float* x0b = x0 + (size_t)b * C * NPIX;
    const float* x1b = x1 + (size_t)b * C * NPIX;
    const float* x2b = x2 + (size_t)b * C * NPIX;
    const float* x3b = x3 + (size_t)b * C * NPIX;

    f32x4 acc[3][3];
#pragma unroll
    for (int mt = 0; mt < 3; ++mt)
#pragma unroll
        for (int nt = 0; nt < 3; ++nt)
            acc[mt][nt] = (f32x4){0.f, 0.f, 0.f, 0.f};

    int scr = tid >> 4;            // 0..15: ch sub-row
    int n4 = (tid & 15) * 4;       // n offset within 64

    for (int sub = 0; sub < 8; ++sub) {
        int nb = n0 + sub * 64;
        __syncthreads();
#pragma unroll
        for (int it = 0; it < 12; ++it) {
            int ch = scr + it * 16;
            int s = ch / C, c = ch - s * C;
            const float* xp = (s == 0) ? x0b : (s == 1) ? x1b : (s == 2) ? x2b : x3b;
            float4 v = *(const float4*)(xp + (size_t)c * NPIX + nb + n4);
            unsigned h01 = pkbf(v.x, v.y), h23 = pkbf(v.z, v.w);
            float r0 = v.x - lo2f(h01), r1 = v.y - hi2f(h01);
            float r2 = v.z - lo2f(h23), r3 = v.w - hi2f(h23);
            unsigned l01 = pkbf(r0, r1), l23 = pkbf(r2, r3);
            *(unsigned*)&hibuf[ch * 72 + n4]     = h01;
            *(unsigned*)&hibuf[ch * 72 + n4 + 2] = h23;
            *(unsigned*)&lobuf[ch * 72 + n4]     = l01;
            *(unsigned*)&lobuf[ch * 72 + n4 + 2] = l23;
        }
        __syncthreads();
#pragma unroll
        for (int kb = 0; kb < 2; ++kb) {
            int ko = kb * 32 + quad * 8;
            short8 ah[3], al[3], bh[3], bl[3];
#pragma unroll
            for (int mt = 0; mt < 3; ++mt) {
                ah[mt] = *(const short8*)&hibuf[(mt * 16 + col) * 72 + ko];
                al[mt] = *(const short8*)&lobuf[(mt * 16 + col) * 72 + ko];
            }
#pragma unroll
            for (int nt = 0; nt < 3; ++nt) {
                int row = (wid * 3 + nt) * 16 + col;
                bh[nt] = *(const short8*)&hibuf[row * 72 + ko];
                bl[nt] = *(const short8*)&lobuf[row * 72 + ko];
            }
#pragma unroll
            for (int mt = 0; mt < 3; ++mt)
#pragma unroll
                for (int nt = 0; nt < 3; ++nt) {
                    acc[mt][nt] = __builtin_amdgcn_mfma_f32_16x16x32_bf16(
                        ah[mt], bh[nt], acc[mt][nt], 0, 0, 0);
                    acc[mt][nt] = __builtin_amdgcn_mfma_f32_16x16x32_bf16(
                        ah[mt], bl[nt], acc[mt][nt], 0, 0, 0);
                    acc[mt][nt] = __builtin_amdgcn_mfma_f32_16x16x32_bf16(
                        al[mt], bh[nt], acc[mt][nt], 0, 0, 0);
                }
        }
    }
#pragma unroll
    for (int mt = 0; mt < 3; ++mt)
#pragma unroll
        for (int nt = 0; nt < 3; ++nt) {
            int g = (wid * 3 + nt) * 16 + col;        // 0..191 = s*48 + d
            int s = g / C, d = g - s * C;
#pragma unroll
            for (int j = 0; j < 4; ++j) {
                int c = mt * 16 + quad * 4 + j;
                atomicAdd(&G[(((size_t)s * BATCH + b) * C + c) * C + d],
                          acc[mt][nt][j]);
            }
        }
}

// ---------------------------------------------------------------- k_small
__global__ __launch_bounds__(256) void k_small(
    const float* __restrict__ G,
    const float* __restrict__ Wa, const float* __restrict__ Wb,
    const float* __restrict__ Wc, const float* __restrict__ Wd,
    const float* __restrict__ fuse_w, float* __restrict__ M2g)
{
    int s = blockIdx.x, b = blockIdx.y;
    const float* Ws = (s == 0) ? Wa : (s == 1) ? Wb : (s == 2) ? Wc : Wd;

    __shared__ float g[C * C], wsm[C * C], wam[C * C], fw[C * C];
    __shared__ float t[C * C], e[C * C], m[C * C];
    int tid = threadIdx.x;

    const float* Gb = G + ((size_t)s * BATCH + b) * C * C;
    for (int k = tid; k < C * C; k += 256) {
        g[k] = Gb[k];
        wsm[k] = Ws[k];
        wam[k] = Wa[k];
        int o = k / C, c = k % C;
        fw[k] = fuse_w[(size_t)o * C4 + s * C + c];
    }
    __syncthreads();

    for (int k = tid; k < C * C; k += 256) {
        int c = k / C, d = k % C;
        float a = 0.f;
        for (int q = 0; q < C; ++q) a += g[c * C + q] * wsm[d * C + q];
        t[k] = a;
    }
    __syncthreads();
    for (int k = tid; k < C * C; k += 256) {
        int c = k / C, d = k % C;
        float a = 0.f;
        for (int q = 0; q < C; ++q) a += wam[c * C + q] * t[q * C + d];
        e[k] = a;
    }
    __syncthreads();
    if (tid < C) {
        int c = tid;
        float mn = e[c * C];
        for (int d = 1; d < C; ++d) mn = fminf(mn, e[c * C + d]);
        float sum = 0.f;
        for (int d = 0; d < C; ++d) {
            float v = __expf(mn - e[c * C + d]);
            e[c * C + d] = v;
            sum += v;
        }
        float inv = 1.0f / sum;
        for (int d = 0; d < C; ++d) e[c * C + d] *= inv;
    }
    __syncthreads();
    for (int k = tid; k < C * C; k += 256) {
        int d = k / C, o = k % C;
        float a = 0.f;
        for (int q = 0; q < C; ++q) a += fw[o * C + q] * e[q * C + d];
        m[k] = a;
    }
    __syncthreads();
    float* out = M2g + ((size_t)b * 4 + s) * C * C;
    for (int k = tid; k < C * C; k += 256) {
        int c = k / C, o = k % C;
        float a = 0.f;
        for (int q = 0; q < C; ++q) a += wsm[q * C + c] * m[q * C + o];
        out[k] = a;
    }
}

// ---------------------------------------------------------------- k_apply_mfma
// apre[b,o,n] = sum_{s,c} M2[b][s][c][o] * Xs[b,c,n] + fuse_b[o]  via MFMA.
// A = M2 (K padded 192->256, 64 per source), frags hoisted from LDS.
// B = Xs loaded direct from global fp32 (coalesced 64B runs), packed to bf16.
__global__ __launch_bounds__(256) void k_apply_mfma(
    const float* __restrict__ x0, const float* __restrict__ x1,
    const float* __restrict__ x2, const float* __restrict__ x3,
    const float* __restrict__ M2g, const float* __restrict__ fuse_b,
    float* __restrict__ apre, float* __restrict__ stats)
{
    __shared__ short Abuf[C * 264];    // [o][k'=s*64+c], zero-padded c>=48
    int b = blockIdx.y;
    int n0 = blockIdx.x * 512;
    int tid = threadIdx.x;
    int wid = tid >> 6, lane = tid & 63, col = lane & 15, quad = lane >> 4;

    const float* x0b = x0 + (size_t)b * C * NPIX;
    const float* x1b = x1 + (size_t)b * C * NPIX;
    const float* x2b = x2 + (size_t)b * C * NPIX;
    const float* x3b = x3 + (size_t)b * C * NPIX;

    const float* Mb = M2g + (size_t)b * 4 * C * C;
    for (int e = tid; e < C * 256; e += 256) {
        int o = e >> 8, k = e & 255;
        int s = k >> 6, c = k & 63;
        float v = (c < C) ? Mb[((size_t)(s * C + c)) * C + o] : 0.f;
        Abuf[o * 264 + k] = f2bfs(v);
    }
    __syncthreads();

    short8 afr[3][8];
#pragma unroll
    for (int mt = 0; mt < 3; ++mt)
#pragma unroll
        for (int kq = 0; kq < 8; ++kq)
            afr[mt][kq] = *(const short8*)&Abuf[(mt * 16 + col) * 264 + kq * 32 + quad * 8];

    float fbv[3][4];
#pragma unroll
    for (int mt = 0; mt < 3; ++mt)
#pragma unroll
        for (int j = 0; j < 4; ++j)
            fbv[mt][j] = fuse_b[mt * 16 + quad * 4 + j];

    float s1[3][4] = {}, s2[3][4] = {};

    for (int sub = 0; sub < 8; ++sub) {
        int n = n0 + wid * 128 + sub * 16 + col;
        f32x4 acc[3];
#pragma unroll
        for (int mt = 0; mt < 3; ++mt) acc[mt] = (f32x4){0.f, 0.f, 0.f, 0.f};

#pragma unroll
        for (int kq = 0; kq < 8; ++kq) {
            const int s = kq >> 1;                      // compile-time under unroll
            int c0 = (kq & 1) * 32 + quad * 8;
            short8 bfr = {0, 0, 0, 0, 0, 0, 0, 0};
            if (c0 < C) {
                const float* p = ((s == 0) ? x0b : (s == 1) ? x1b : (s == 2) ? x2b : x3b)
                                 + (size_t)c0 * NPIX + n;
                float v0 = p[0 * NPIX], v1 = p[1 * NPIX], v2 = p[2 * NPIX], v3 = p[3 * NPIX];
                float v4 = p[4 * NPIX], v5 = p[5 * NPIX], v6 = p[6 * NPIX], v7 = p[7 * NPIX];
                union { short8 s8; unsigned u[4]; } t;
                t.u[0] = pkbf(v0, v1); t.u[1] = pkbf(v2, v3);
                t.u[2] = pkbf(v4, v5); t.u[3] = pkbf(v6, v7);
                bfr = t.s8;
            }
#pragma unroll
            for (int mt = 0; mt < 3; ++mt)
                acc[mt] = __builtin_amdgcn_mfma_f32_16x16x32_bf16(
                    afr[mt][kq], bfr, acc[mt], 0, 0, 0);
        }
#pragma unroll
        for (int mt = 0; mt < 3; ++mt)
#pragma unroll
            for (int j = 0; j < 4; ++j) {
                int o = mt * 16 + quad * 4 + j;
                float val = acc[mt][j] + fbv[mt][j];
                apre[((size_t)b * C + o) * NPIX + n] = val;
                s1[mt][j] += val;
                s2[mt][j] += val * val;
            }
    }
#pragma unroll
    for (int mt = 0; mt < 3; ++mt)
#pragma unroll
        for (int j = 0; j < 4; ++j) {
            float a = s1[mt][j], q = s2[mt][j];
#pragma unroll
            for (int off = 8; off; off >>= 1) {
                a += __shfl_down(a, off, 16);
                q += __shfl_down(q, off, 16);
            }
            if (col == 0) {
                int o = mt * 16 + quad * 4 + j;
                atomicAdd(&stats[o], a);
                atomicAdd(&stats[C + o], q);
            }
        }
}

// ---------------------------------------------------------------- k_bn1t
// mid_t[b,px,c] = bf16(gamma_cam*relu(BN(apre)) + input); LDS tile-transpose
// makes the global bf16 store a contiguous short4 stream.
__global__ __launch_bounds__(256) void k_bn1t(
    const float* __restrict__ apre, const float* __restrict__ inp,
    const float* __restrict__ stats, const float* __restrict__ gamma,
    const float* __restrict__ beta, const float* __restrict__ gcam,
    short* __restrict__ mid_t)
{
    __shared__ short t[64 * C];     // [px_local][c]
    int b = blockIdx.y;
    int n0 = blockIdx.x * 64;
    int tid = threadIdx.x;
    const float invc = 1.0f / (float)CNT;
    float g = gcam[0];

#pragma unroll
    for (int it = 0; it < 3; ++it) {
        int e = tid + it * 256;                 // 0..767 = 48 ch x 16 px-quads
        int c = e >> 4, pq = (e & 15) * 4;
        float mu = stats[c] * invc;
        float var = stats[C + c] * invc - mu * mu;
        float sc = gamma[c] * rsqrtf(var + 1e-5f);
        float be = beta[c] - mu * sc;
        size_t base = ((size_t)b * C + c) * NPIX + n0 + pq;
        float4 v = *(const float4*)(apre + base);
        float4 x = *(const float4*)(inp + base);
        t[(pq + 0) * C + c] = f2bfs(fmaxf(v.x * sc + be, 0.f) * g + x.x);
        t[(pq + 1) * C + c] = f2bfs(fmaxf(v.y * sc + be, 0.f) * g + x.y);
        t[(pq + 2) * C + c] = f2bfs(fmaxf(v.z * sc + be, 0.f) * g + x.z);
        t[(pq + 3) * C + c] = f2bfs(fmaxf(v.w * sc + be, 0.f) * g + x.w);
    }
    __syncthreads();
    short* mb = mid_t + ((size_t)b * NPIX + n0) * C;
#pragma unroll
    for (int it = 0; it < 3; ++it) {
        int e = tid + it * 256;                 // contiguous: row = 12 short4s
        *(short4*)(mb + e * 4) = *(const short4*)&t[e * 4];
    }
}

// ---------------------------------------------------------------- k_prep
__global__ __launch_bounds__(256) void k_prep(
    const float* __restrict__ outw, short* __restrict__ Wb)
{
    int idx = blockIdx.x * 256 + threadIdx.x;
    if (idx >= 9 * 48 * 64) return;
    int i = idx & 63;
    int o = (idx >> 6) % 48;
    int tap = idx / (64 * 48);
    float v = (i < C) ? outw[((size_t)o * C + i) * 9 + tap] : 0.f;
    Wb[idx] = f2bfs(v);
}

// ---------------------------------------------------------------- k_conv_mfma
__global__ __launch_bounds__(256) void k_conv_mfma(
    const short* __restrict__ mid_t, const short* __restrict__ Wb,
    const float* __restrict__ bias, float* __restrict__ out,
    float* __restrict__ stats)
{
    __shared__ short xl[324 * 72];
    __shared__ float sst[96];
    int b = blockIdx.y;
    int ty = blockIdx.x / 12, tx = blockIdx.x % 12;
    int h0 = ty * 16, w0 = tx * 16;
    int tid = threadIdx.x;

    if (tid < 96) sst[tid] = 0.f;

    for (int ch = tid; ch < 2916; ch += 256) {
        int lpx = ch / 9, part = ch % 9;
        int hh = h0 - 1 + lpx / 18, ww = w0 - 1 + lpx % 18;
        short8 v = {0, 0, 0, 0, 0, 0, 0, 0};
        if (part < 6 && hh >= 0 && hh < HW && ww >= 0 && ww < HW)
            v = *(const short8*)(mid_t + ((size_t)b * NPIX + hh * HW + ww) * C + part * 8);
        *(short8*)(xl + lpx * 72 + part * 8) = v;
    }
    __syncthreads();

    int wid = tid >> 6, lane = tid & 63;
    int col = lane & 15, quad = lane >> 4;

    f32x4 acc[3][4];
#pragma unroll
    for (int mt = 0; mt < 3; ++mt)
#pragma unroll
        for (int rr = 0; rr < 4; ++rr)
            acc[mt][rr] = (f32x4){0.f, 0.f, 0.f, 0.f};

#pragma unroll
    for (int tap = 0; tap < 9; ++tap) {
        int dh = tap / 3, dw = tap % 3;
#pragma unroll
        for (int kb = 0; kb < 2; ++kb) {
            short8 afr[3];
#pragma unroll
            for (int mt = 0; mt < 3; ++mt)
                afr[mt] = *(const short8*)(Wb + ((size_t)(tap * 48 + mt * 16 + col)) * 64
                                               + kb * 32 + quad * 8);
#pragma unroll
            for (int rr = 0; rr < 4; ++rr) {
                int r = wid * 4 + rr;
                int lpx = (r + dh) * 18 + col + dw;
                short8 bfr = *(const short8*)(xl + lpx * 72 + kb * 32 + quad * 8);
#pragma unroll
                for (int mt = 0; mt < 3; ++mt)
                    acc[mt][rr] = __builtin_amdgcn_mfma_f32_16x16x32_bf16(
                        afr[mt], bfr, acc[mt][rr], 0, 0, 0);
            }
        }
    }

    float s1[3][4] = {}, s2[3][4] = {};
#pragma unroll
    for (int mt = 0; mt < 3; ++mt)
#pragma unroll
        for (int rr = 0; rr < 4; ++rr) {
            int r = wid * 4 + rr;
            f32x4 v = acc[mt][rr];
#pragma unroll
            for (int j = 0; j < 4; ++j) {
                int o = mt * 16 + quad * 4 + j;
                float val = v[j] + bias[o];
                out[((size_t)b * C + o) * NPIX + (h0 + r) * HW + w0 + col] = val;
                s1[mt][j] += val;
                s2[mt][j] += val * val;
            }
        }
#pragma unroll
    for (int mt = 0; mt < 3; ++mt)
#pragma unroll
        for (int j = 0; j < 4; ++j) {
            float a = s1[mt][j], q = s2[mt][j];
#pragma unroll
            for (int off = 8; off; off >>= 1) {
                a += __shfl_down(a, off, 16);
                q += __shfl_down(q, off, 16);
            }
            if (col == 0) {
                int o = mt * 16 + quad * 4 + j;
                atomicAdd(&sst[o], a);
                atomicAdd(&sst[48 + o], q);
            }
        }
    __syncthreads();
    if (tid < 48)       atomicAdd(&stats[2 * C + tid], sst[tid]);
    else if (tid < 96)  atomicAdd(&stats[3 * C + tid - 48], sst[tid]);
}

// ---------------------------------------------------------------- k_bn2
__global__ __launch_bounds__(256) void k_bn2(
    float* __restrict__ out, const float* __restrict__ stats,
    const float* __restrict__ gamma, const float* __restrict__ beta)
{
    size_t i = ((size_t)blockIdx.x * 256 + threadIdx.x) * 4;
    int c = (int)((i / NPIX) % C);
    const float invc = 1.0f / (float)CNT;
    float mu = stats[2 * C + c] * invc;
    float var = stats[3 * C + c] * invc - mu * mu;
    float sc = gamma[c] * rsqrtf(var + 1e-5f);
    float be = beta[c] - mu * sc;

    float4 v = *(float4*)(out + i);
    v.x = fmaxf(v.x * sc + be, 0.f);
    v.y = fmaxf(v.y * sc + be, 0.f);
    v.z = fmaxf(v.z * sc + be, 0.f);
    v.w = fmaxf(v.w * sc + be, 0.f);
    *(float4*)(out + i) = v;
}

// ---------------------------------------------------------------- launch
extern "C" void kernel_launch(void* const* d_in, const int* in_sizes, int n_in,
                              void* d_out, int out_size, void* d_ws, size_t ws_size,
                              hipStream_t stream)
{
    const float* inp   = (const float*)d_in[0];
    const float* fb    = (const float*)d_in[1];
    const float* fc    = (const float*)d_in[2];
    const float* fd    = (const float*)d_in[3];
    const float* Wa    = (const float*)d_in[4];
    const float* Wbm   = (const float*)d_in[5];
    const float* Wcm   = (const float*)d_in[6];
    const float* Wdm   = (const float*)d_in[7];
    const float* fusew = (const float*)d_in[8];
    const float* fuseb = (const float*)d_in[9];
    const float* fgam  = (const float*)d_in[10];
    const float* fbet  = (const float*)d_in[11];
    const float* gcam  = (const float*)d_in[12];
    const float* outw  = (const float*)d_in[13];
    const float* outb  = (const float*)d_in[14];
    const float* ogam  = (const float*)d_in[15];
    const float* obet  = (const float*)d_in[16];

    float* ws    = (float*)d_ws;
    float* apre  = ws + APRE_OFF;
    float* G     = ws + G_OFF;
    float* stats = ws + STATS_OFF;
    float* M2g   = ws + M2_OFF;
    short* mid_t = (short*)((char*)d_ws + MIDT_BYTE);
    short* Wb    = (short*)((char*)d_ws + WB_BYTE);
    float* out   = (float*)d_out;

    hipMemsetAsync(G, 0, (73728ull + 192ull) * sizeof(float), stream);

    k_prep<<<108, 256, 0, stream>>>(outw, Wb);
    k_gram_mfma<<<dim3(72, BATCH), 256, 0, stream>>>(inp, fb, fc, fd, G);
    k_small<<<dim3(4, BATCH), 256, 0, stream>>>(G, Wa, Wbm, Wcm, Wdm, fusew, M2g);
    k_apply_mfma<<<dim3(72, BATCH), 256, 0, stream>>>(inp, fb, fc, fd, M2g, fuseb, apre, stats);
    k_bn1t<<<dim3(576, BATCH), 256, 0, stream>>>(apre, inp, stats, fgam, fbet, gcam, mid_t);
    k_conv_mfma<<<dim3(144, BATCH), 256, 0, stream>>>(mid_t, Wb, outb, out, stats);
    k_bn2<<<13824, 256, 0, stream>>>(out, stats, ogam, obet);
}